// Round 4
// baseline (356.966 us; speedup 1.0000x reference)
//
#include <hip/hip_runtime.h>
#include <stdint.h>
#include <math.h>

// Problem constants
#define NN   20000
#define EE   320000
#define HH   128
#define MSTR 136            // h1/mij LDS row stride (u16)
#define ARSTR 72            // attr+rbf LDS row stride (u16)

typedef __attribute__((ext_vector_type(8))) short          bf16x8;
typedef __attribute__((ext_vector_type(4))) float          f32x4;
typedef unsigned short u16;

// fp32 -> bf16 round-to-nearest-even
__device__ __forceinline__ u16 f2b(float f) {
  union { float f; unsigned int u; } v; v.f = f;
  return (u16)((v.u + 0x7fffu + ((v.u >> 16) & 1u)) >> 16);
}
__device__ __forceinline__ bf16x8 cvt8(float4 a, float4 b) {
  bf16x8 r;
  r[0] = (short)f2b(a.x); r[1] = (short)f2b(a.y);
  r[2] = (short)f2b(a.z); r[3] = (short)f2b(a.w);
  r[4] = (short)f2b(b.x); r[5] = (short)f2b(b.y);
  r[6] = (short)f2b(b.z); r[7] = (short)f2b(b.w);
  return r;
}

// packed bf16x2 atomic add (CDNA4 global_atomic_pk_add_bf16), fire-and-forget
__device__ __forceinline__ void pk_atomic_bf16(u16* addr, unsigned int data) {
  asm volatile("global_atomic_pk_add_bf16 %0, %1, off"
               :
               : "v"((unsigned long long)(uintptr_t)addr), "v"(data)
               : "memory");
}

// ---------------------------------------------------------------------------
// prep: bf16 weights packed for per-wave coalesced fragment loads:
//   pack[kc][nt][l][j], lane l loads pack + kc*4096 + nt*512 + l*8 (16B/lane)
//   value = W[k = kc*32 + (l>>4)*8 + j][n = nt*16 + (l&15)]
// ew1 K-rows permuted to feat order (hi | hj | attr | rbf | pad).
// ---------------------------------------------------------------------------
__global__ void prep_kernel(const float* __restrict__ ew1, const float* __restrict__ ew2,
                            const float* __restrict__ xw1, const float* __restrict__ nw1,
                            const float* __restrict__ nw2,
                            u16* __restrict__ ew1c, u16* __restrict__ ew2c,
                            u16* __restrict__ xw1c, u16* __restrict__ nw1c,
                            u16* __restrict__ nw2c) {
  int idx = blockIdx.x * 256 + threadIdx.x;
  int i2, n, k;
  u16* dst;
  const float* src;
  if (idx < 40960)       { i2 = idx;          dst = ew1c; src = ew1; }
  else if (idx < 57344)  { i2 = idx - 40960;  dst = ew2c; src = ew2; }
  else if (idx < 73728)  { i2 = idx - 57344;  dst = xw1c; src = xw1; }
  else if (idx < 106496) { i2 = idx - 73728;  dst = nw1c; src = nw1; }
  else if (idx < 122880) { i2 = idx - 106496; dst = nw2c; src = nw2; }
  else return;
  {
    int kc = i2 >> 12, rem = i2 & 4095, nt = rem >> 9, rem2 = rem & 511;
    int l = rem2 >> 3, j = rem2 & 7;
    n = nt * 16 + (l & 15);
    k = kc * 32 + (l >> 4) * 8 + j;
  }
  float v;
  if (dst == ew1c) {
    if (k < 256)      v = src[(k + 48) * HH + n];
    else if (k < 304) v = src[(k - 256) * HH + n];
    else              v = 0.0f;
  } else {
    v = src[k * HH + n];
  }
  dst[i2] = f2b(v);
}

// ---------------------------------------------------------------------------
// edge kernel: 64 edges/block, 256 threads (4 waves x 16 rows).
// feat (hi|hj|attr|rbf) -> GEMM1(relu) -> GEMM2(relu)=mij -> overlay mij
// -> GEMM3 -> xg -> dx atomics -> eij -> mi pk-bf16 atomics (all atomics LAST,
// after the final barrier, so no s_barrier ever drains the atomic queue).
// ---------------------------------------------------------------------------
__global__ __launch_bounds__(256, 4) void edge_kernel(
    const float* __restrict__ h, const float* __restrict__ x,
    const float* __restrict__ edge_attr,
    const u16* __restrict__ ew1c, const float* __restrict__ eb1,
    const u16* __restrict__ ew2c, const float* __restrict__ eb2,
    const float* __restrict__ inf_w, const float* __restrict__ inf_b,
    const u16* __restrict__ xw1c, const float* __restrict__ xb1,
    const float* __restrict__ xw2, const float* __restrict__ xb2,
    const int* __restrict__ edge_index,
    u16* __restrict__ mi, float* __restrict__ dx) {
  __shared__ u16 ar_s[64 * ARSTR];
  __shared__ u16 h1_s[64 * MSTR];
  __shared__ float relx_s[64][4];
  __shared__ int dst_s[64];
  __shared__ int src_s[64];

  const int t   = threadIdx.x;
  const int w   = t >> 6;
  const int l   = t & 63;
  const int l15 = l & 15;
  const int q   = l >> 4;
  const int e0  = blockIdx.x * 64;
  const int myrow = w * 16 + l15;

  if (t < 64) {
    int d = edge_index[e0 + t];
    int s = edge_index[EE + e0 + t];
    dst_s[t] = d; src_s[t] = s;
    float rx = x[d * 3 + 0] - x[s * 3 + 0];
    float ry = x[d * 3 + 1] - x[s * 3 + 1];
    float rz = x[d * 3 + 2] - x[s * 3 + 2];
    relx_s[t][0] = rx; relx_s[t][1] = ry; relx_s[t][2] = rz;
    relx_s[t][3] = sqrtf(rx * rx + ry * ry + rz * rz);
  }
  __syncthreads();

  const int dstv = dst_s[myrow];
  const int srcv = src_s[myrow];
  const float* hd = h + (size_t)dstv * HH;
  const float* hs = h + (size_t)srcv * HH;
  float4 t0[8], t1[8];
  #pragma unroll
  for (int c = 0; c < 4; ++c) {
    t0[c]     = *(const float4*)&hd[c * 32 + q * 8];
    t1[c]     = *(const float4*)&hd[c * 32 + q * 8 + 4];
    t0[4 + c] = *(const float4*)&hs[c * 32 + q * 8];
    t1[4 + c] = *(const float4*)&hs[c * 32 + q * 8 + 4];
  }

  const float step  = 100.0f / 19.0f;
  const float coeff = -0.5f / (step * step);
  for (int idx = t; idx < 64 * 64; idx += 256) {
    int e = idx >> 6, c = idx & 63;
    float v = 0.0f;
    if (c < 28)      v = edge_attr[(size_t)(e0 + e) * 28 + c];
    else if (c < 48) { float d = relx_s[e][3] - (float)(c - 28) * step; v = __expf(coeff * d * d); }
    ar_s[e * ARSTR + c] = f2b(v);
  }
  __syncthreads();

  bf16x8 afrag[10];
  #pragma unroll
  for (int c = 0; c < 8; ++c) afrag[c] = cvt8(t0[c], t1[c]);
  afrag[8] = *(const bf16x8*)&ar_s[myrow * ARSTR + q * 8];
  afrag[9] = *(const bf16x8*)&ar_s[myrow * ARSTR + 32 + q * 8];

  // ---- GEMM1 ----
  f32x4 acc[8];
  #pragma unroll
  for (int nt = 0; nt < 8; ++nt) acc[nt] = (f32x4){0.f, 0.f, 0.f, 0.f};
  #pragma unroll
  for (int kc = 0; kc < 10; ++kc) {
    const u16* bp = ew1c + (kc << 12) + l * 8;
    #pragma unroll
    for (int nt = 0; nt < 8; ++nt) {
      bf16x8 b = *(const bf16x8*)(bp + nt * 512);
      acc[nt] = __builtin_amdgcn_mfma_f32_16x16x32_bf16(afrag[kc], b, acc[nt], 0, 0, 0);
    }
  }
  #pragma unroll
  for (int nt = 0; nt < 8; ++nt) {
    float b1 = eb1[nt * 16 + l15];
    #pragma unroll
    for (int r = 0; r < 4; ++r) {
      float v = acc[nt][r] + b1; v = v > 0.f ? v : 0.f;
      h1_s[(w * 16 + q * 4 + r) * MSTR + nt * 16 + l15] = f2b(v);
    }
  }
  __syncthreads();

  // ---- GEMM2 -> mijv (regs) ----
  bf16x8 a2[4];
  #pragma unroll
  for (int kc = 0; kc < 4; ++kc)
    a2[kc] = *(const bf16x8*)&h1_s[myrow * MSTR + kc * 32 + q * 8];
  #pragma unroll
  for (int nt = 0; nt < 8; ++nt) acc[nt] = (f32x4){0.f, 0.f, 0.f, 0.f};
  #pragma unroll
  for (int kc = 0; kc < 4; ++kc) {
    const u16* bp = ew2c + (kc << 12) + l * 8;
    #pragma unroll
    for (int nt = 0; nt < 8; ++nt) {
      bf16x8 b = *(const bf16x8*)(bp + nt * 512);
      acc[nt] = __builtin_amdgcn_mfma_f32_16x16x32_bf16(a2[kc], b, acc[nt], 0, 0, 0);
    }
  }
  float mijv[8][4];
  #pragma unroll
  for (int nt = 0; nt < 8; ++nt) {
    float b2 = eb2[nt * 16 + l15];
    #pragma unroll
    for (int r = 0; r < 4; ++r) {
      float v = acc[nt][r] + b2;
      mijv[nt][r] = v > 0.f ? v : 0.f;
    }
  }
  __syncthreads();                 // all h1_s (GEMM1) reads complete
  #pragma unroll
  for (int nt = 0; nt < 8; ++nt)
    #pragma unroll
    for (int r = 0; r < 4; ++r)
      h1_s[(w * 16 + q * 4 + r) * MSTR + nt * 16 + l15] = f2b(mijv[nt][r]);
  __syncthreads();                 // mij tile fully written (no atomics yet!)

  // ---- GEMM3: A = mij (LDS), B = xw1c ----
  bf16x8 a3[4];
  #pragma unroll
  for (int kc = 0; kc < 4; ++kc)
    a3[kc] = *(const bf16x8*)&h1_s[myrow * MSTR + kc * 32 + q * 8];
  #pragma unroll
  for (int nt = 0; nt < 8; ++nt) acc[nt] = (f32x4){0.f, 0.f, 0.f, 0.f};
  #pragma unroll
  for (int kc = 0; kc < 4; ++kc) {
    const u16* bp = xw1c + (kc << 12) + l * 8;
    #pragma unroll
    for (int nt = 0; nt < 8; ++nt) {
      bf16x8 b = *(const bf16x8*)(bp + nt * 512);
      acc[nt] = __builtin_amdgcn_mfma_f32_16x16x32_bf16(a3[kc], b, acc[nt], 0, 0, 0);
    }
  }

  // ---- xg row-reduce + dx atomics (no barrier after this point) ----
  float xv[8], b3[8];
  #pragma unroll
  for (int nt = 0; nt < 8; ++nt) { xv[nt] = xw2[nt * 16 + l15]; b3[nt] = xb1[nt * 16 + l15]; }
  float xb2_0 = xb2[0];
  #pragma unroll
  for (int r = 0; r < 4; ++r) {
    float p = 0.f;
    #pragma unroll
    for (int nt = 0; nt < 8; ++nt) {
      float v = acc[nt][r] + b3[nt]; v = v > 0.f ? v : 0.f;
      p += v * xv[nt];
    }
    p += __shfl_xor(p, 1, 16);
    p += __shfl_xor(p, 2, 16);
    p += __shfl_xor(p, 4, 16);
    p += __shfl_xor(p, 8, 16);
    float xg = p + xb2_0;
    int row = w * 16 + q * 4 + r;
    if (l15 < 3) atomicAdd(&dx[(size_t)dst_s[row] * 3 + l15], relx_s[row][l15] * xg);
  }

  // ---- eij + mi packed-bf16 atomics (issued last, drained only at endpgm) ----
  float iw[8];
  #pragma unroll
  for (int nt = 0; nt < 8; ++nt) iw[nt] = inf_w[nt * 16 + l15];
  float ib = inf_b[0];
  float eijv[4];
  #pragma unroll
  for (int r = 0; r < 4; ++r) {
    float p = 0.f;
    #pragma unroll
    for (int nt = 0; nt < 8; ++nt) p += mijv[nt][r] * iw[nt];
    p += __shfl_xor(p, 1, 16);
    p += __shfl_xor(p, 2, 16);
    p += __shfl_xor(p, 4, 16);
    p += __shfl_xor(p, 8, 16);
    eijv[r] = 1.0f / (1.0f + __expf(-(p + ib)));
  }
  #pragma unroll
  for (int r = 0; r < 4; ++r) {
    int row = w * 16 + q * 4 + r;
    u16* base = mi + (size_t)dst_s[row] * HH;
    #pragma unroll
    for (int nt = 0; nt < 8; ++nt) {
      float v  = mijv[nt][r] * eijv[r];
      float vp = __shfl_xor(v, 1);          // partner column (l15 ^ 1)
      if ((l15 & 1) == 0) {
        unsigned int packed = (unsigned int)f2b(v) | ((unsigned int)f2b(vp) << 16);
        pk_atomic_bf16(base + nt * 16 + l15, packed);
      }
    }
  }
}

// ---------------------------------------------------------------------------
// node kernel: out = relu([mi,h]@nw1+nb1)@nw2+nb2 ; x_out = x + dx/E
// mi is bf16 -> A fragments are direct u16x8 loads (no cvt).
// ---------------------------------------------------------------------------
__global__ __launch_bounds__(256, 4) void node_kernel(
    const float* __restrict__ h, const float* __restrict__ x,
    const u16* __restrict__ nw1c, const float* __restrict__ nb1,
    const u16* __restrict__ nw2c, const float* __restrict__ nb2,
    const u16* __restrict__ mi, const float* __restrict__ dx,
    float* __restrict__ out) {
  __shared__ u16 h1_s[64 * MSTR];
  const int t = threadIdx.x;
  const int w = t >> 6;
  const int l = t & 63;
  const int l15 = l & 15;
  const int q = l >> 4;
  const int r0 = blockIdx.x * 64;
  const int myrow = w * 16 + l15;
  const int grow = r0 + myrow;
  const int gr = grow < NN ? grow : NN - 1;

  const u16*   mp = mi + (size_t)gr * HH;
  const float* hp = h + (size_t)gr * HH;
  bf16x8 afrag[8];
  #pragma unroll
  for (int c = 0; c < 4; ++c) {
    afrag[c] = *(const bf16x8*)&mp[c * 32 + q * 8];
    float4 b0 = *(const float4*)&hp[c * 32 + q * 8];
    float4 b1 = *(const float4*)&hp[c * 32 + q * 8 + 4];
    afrag[4 + c] = cvt8(b0, b1);
  }
  f32x4 acc[8];
  #pragma unroll
  for (int nt = 0; nt < 8; ++nt) acc[nt] = (f32x4){0.f, 0.f, 0.f, 0.f};
  #pragma unroll
  for (int kc = 0; kc < 8; ++kc) {
    const u16* bp = nw1c + (kc << 12) + l * 8;
    #pragma unroll
    for (int nt = 0; nt < 8; ++nt) {
      bf16x8 b = *(const bf16x8*)(bp + nt * 512);
      acc[nt] = __builtin_amdgcn_mfma_f32_16x16x32_bf16(afrag[kc], b, acc[nt], 0, 0, 0);
    }
  }
  #pragma unroll
  for (int nt = 0; nt < 8; ++nt) {
    float b1 = nb1[nt * 16 + l15];
    #pragma unroll
    for (int r = 0; r < 4; ++r) {
      float v = acc[nt][r] + b1; v = v > 0.f ? v : 0.f;
      h1_s[(w * 16 + q * 4 + r) * MSTR + nt * 16 + l15] = f2b(v);
    }
  }
  __syncthreads();
  bf16x8 a2[4];
  #pragma unroll
  for (int kc = 0; kc < 4; ++kc)
    a2[kc] = *(const bf16x8*)&h1_s[myrow * MSTR + kc * 32 + q * 8];
  #pragma unroll
  for (int nt = 0; nt < 8; ++nt) acc[nt] = (f32x4){0.f, 0.f, 0.f, 0.f};
  #pragma unroll
  for (int kc = 0; kc < 4; ++kc) {
    const u16* bp = nw2c + (kc << 12) + l * 8;
    #pragma unroll
    for (int nt = 0; nt < 8; ++nt) {
      bf16x8 b = *(const bf16x8*)(bp + nt * 512);
      acc[nt] = __builtin_amdgcn_mfma_f32_16x16x32_bf16(a2[kc], b, acc[nt], 0, 0, 0);
    }
  }
  #pragma unroll
  for (int nt = 0; nt < 8; ++nt) {
    float b2 = nb2[nt * 16 + l15];
    #pragma unroll
    for (int r = 0; r < 4; ++r) {
      int gr2 = r0 + w * 16 + q * 4 + r;
      if (gr2 < NN) out[(size_t)gr2 * HH + nt * 16 + l15] = acc[nt][r] + b2;
    }
  }
  if (t < 192) {
    int rr = t / 3, dim = t % 3;
    int gr2 = r0 + rr;
    if (gr2 < NN)
      out[(size_t)NN * HH + (size_t)gr2 * 3 + dim] =
          x[(size_t)gr2 * 3 + dim] + dx[(size_t)gr2 * 3 + dim] * (1.0f / (float)EE);
  }
}

// ---------------------------------------------------------------------------
// launch
// ---------------------------------------------------------------------------
extern "C" void kernel_launch(void* const* d_in, const int* in_sizes, int n_in,
                              void* d_out, int out_size, void* d_ws, size_t ws_size,
                              hipStream_t stream) {
  const float* h         = (const float*)d_in[0];
  const float* x         = (const float*)d_in[1];
  const float* edge_attr = (const float*)d_in[2];
  const float* ew1 = (const float*)d_in[3];
  const float* eb1 = (const float*)d_in[4];
  const float* ew2 = (const float*)d_in[5];
  const float* eb2 = (const float*)d_in[6];
  const float* inf_w = (const float*)d_in[7];
  const float* inf_b = (const float*)d_in[8];
  const float* nw1 = (const float*)d_in[9];
  const float* nb1 = (const float*)d_in[10];
  const float* nw2 = (const float*)d_in[11];
  const float* nb2 = (const float*)d_in[12];
  const float* xw1 = (const float*)d_in[13];
  const float* xb1 = (const float*)d_in[14];
  const float* xw2 = (const float*)d_in[15];
  const float* xb2 = (const float*)d_in[16];
  const int* edge_index = (const int*)d_in[17];
  float* out = (float*)d_out;

  char* wsb = (char*)d_ws;
  u16* ew1c = (u16*)(wsb + 0);          //  81920 B
  u16* ew2c = (u16*)(wsb + 81920);      //  32768 B
  u16* xw1c = (u16*)(wsb + 114688);     //  32768 B
  u16* nw1c = (u16*)(wsb + 147456);     //  65536 B
  u16* nw2c = (u16*)(wsb + 212992);     //  32768 B
  u16*   mi = (u16*)(wsb + 245760);     // 5120000 B (bf16)
  float* dx = (float*)(wsb + 5365760);  //  240000 B  -> total 5605760

  // zero mi (bf16 zeros = 0x0000) + dx
  hipMemsetAsync(wsb + 245760, 0, 5120000 + 240000, stream);

  prep_kernel<<<(122880 + 255) / 256, 256, 0, stream>>>(
      ew1, ew2, xw1, nw1, nw2, ew1c, ew2c, xw1c, nw1c, nw2c);

  edge_kernel<<<EE / 64, 256, 0, stream>>>(
      h, x, edge_attr, ew1c, eb1, ew2c, eb2, inf_w, inf_b,
      xw1c, xb1, xw2, xb2, edge_index, mi, dx);

  node_kernel<<<(NN + 63) / 64, 256, 0, stream>>>(
      h, x, nw1c, nb1, nw2c, nb2, mi, dx, out);
}